// Round 20
// baseline (692.536 us; speedup 1.0000x reference)
//
#include <hip/hip_runtime.h>

typedef _Float16 f16;
typedef _Float16 f16x8 __attribute__((ext_vector_type(8)));
typedef _Float16 f16x4 __attribute__((ext_vector_type(4)));
typedef float    f32x4 __attribute__((ext_vector_type(4)));

#define B_SZ   2048
#define NCH    256
#define L0_    127
#define L1_    125
#define L2_    123
#define L3_    121
#define F1_    512
#define FCK    30976
#define KCH    968         // 30976 / 32 k-chunks
#define SPLIT  22          // split-K for FC1: 968 = 22 * 44 exactly
#define KPS    44
#define NS_FC  22

// async global->LDS, 16B per lane; dest = wave-uniform base + lane*16
__device__ __forceinline__ void gl16(const f16* g, f16* l) {
    __builtin_amdgcn_global_load_lds(
        (const __attribute__((address_space(1))) void*)g,
        (__attribute__((address_space(3))) void*)l, 16, 0, 0);
}

// ---------------------------------------------------------------------------
// merged weight prep, CHUNK-MAJOR [ks32][co][32]:
// wpw: 4 chunks (K=128: [wp1 | wp0]); wct1..3: 24 chunks (kt = k*256+ci)
// ---------------------------------------------------------------------------
__global__ __launch_bounds__(256) void prep_w(const float* __restrict__ Wp,
                                              const float* __restrict__ W1,
                                              const float* __restrict__ W2,
                                              const float* __restrict__ W3,
                                              f16* __restrict__ wpw,
                                              f16* __restrict__ wct1,
                                              f16* __restrict__ wct2,
                                              f16* __restrict__ wct3) {
    int g = blockIdx.x;
    if (g < 128) {
        int idx = g * 256 + threadIdx.x;        // [ck][co][w5]
        int ck = idx >> 13, co = (idx >> 5) & 255, w5 = idx & 31;
        int j = ck * 32 + w5;                   // ci 0..127
        float v = (j < 64) ? Wp[co * 128 + j * 2 + 1]
                           : Wp[co * 128 + (j - 64) * 2];
        wpw[idx] = (f16)v;
        return;
    }
    int g2 = g - 128;
    const float* W = (g2 < 768) ? W1 : (g2 < 1536) ? W2 : W3;
    f16* dst = (g2 < 768) ? wct1 : (g2 < 1536) ? wct2 : wct3;
    int idx = (g2 % 768) * 256 + threadIdx.x;   // [ck][co][w5]
    int ck = idx >> 13, co = (idx >> 5) & 255, w5 = idx & 31;
    int kt = ck * 32 + w5;
    int k = kt >> 8, ci = kt & 255;
    dst[idx] = (f16)W[((size_t)co * NCH + ci) * 3 + k];
}

__global__ __launch_bounds__(256) void prep_wf1k(const float* __restrict__ Wf1,
                                                 f16* __restrict__ wf1h) {
    __shared__ f16 t[NCH * 122];
    const int f = blockIdx.x, tid = threadIdx.x;
    const float* src = Wf1 + (size_t)f * FCK;
    for (int idx = tid; idx < FCK; idx += 256) {
        int co = idx / 121, l = idx - co * 121;
        t[co * 122 + l] = (f16)src[idx];
    }
    __syncthreads();
    f16* dst = wf1h + (size_t)f * FCK;
    for (int idx = tid; idx < FCK; idx += 256) {
        int l = idx >> 8, co = idx & 255;
        dst[idx] = t[co * 122 + l];
    }
}

// ---------------------------------------------------------------------------
// FUSED pw+conv1+conv2+conv3, 2 blocks/CU (the R20 change).
// Block = one b, 256 thr = 4 waves (co quarters), wave tile 128l x 64co.
// ins[128][256] (65,536B) + SINGLE 16KB B buffer = 81,920B = 2 blocks/CU.
// Per chunk: READF(s)->regs; lgkmcnt(0); BAR1 (all waves hold chunk s in
// regs); STAGE(s+1) overwrites the buffer (safe); MFMA(s) hides the stage's
// L2 latency; vmcnt(0); BAR2 (chunk s+1 visible).  The co-resident block
// overlaps the remaining stalls.  A-reads at rows 128/129 (garbage taps of
// discarded acc rows) land in the B-buffer region: finite, harmless.
// ---------------------------------------------------------------------------
#define STAGEC(WT, KS)                                                        \
  { const f16* s0_ = (WT) + (size_t)(KS) * 8192;                              \
    _Pragma("unroll")                                                         \
    for (int j = 0; j < 4; ++j) {                                             \
      int u_ = j * 256 + tid;                                                 \
      int r_ = u_ >> 2, c_ = u_ & 3, cs_ = c_ ^ ((r_ >> 2) & 3);              \
      gl16(s0_ + r_ * 32 + cs_ * 8,                                           \
           wlds + (size_t)(j * 256 + w * 64) * 8); } }

#define READF(FA, FB, KS, CSTEPS)                                             \
  { const int kn_ = (KS) / (CSTEPS), cb_ = ((KS) % (CSTEPS)) * 4;             \
    _Pragma("unroll")                                                         \
    for (int m = 0; m < 8; ++m) {                                             \
      const int r_ = 16 * m + lr + kn_;                                       \
      FA[m] = *(const f16x8*)(ins + r_ * 256                                  \
                              + (((cb_ + lh) ^ (r_ & 7)) << 3)); }            \
    _Pragma("unroll")                                                         \
    for (int n = 0; n < 4; ++n) {                                             \
      const int co_ = wc0 + 16 * n + lr;                                      \
      FB[n] = *(const f16x8*)(wlds                                            \
                + (co_ * 4 + (lh ^ ((co_ >> 2) & 3))) * 8); } }

#define MFMA32(FA, FB)                                                        \
  __builtin_amdgcn_s_setprio(1);                                              \
  _Pragma("unroll")                                                           \
  for (int n = 0; n < 4; ++n)                                                 \
    _Pragma("unroll")                                                         \
    for (int m = 0; m < 8; ++m)                                               \
      acc[m][n] = __builtin_amdgcn_mfma_f32_16x16x32_f16(FA[m], FB[n],        \
                                                         acc[m][n], 0, 0, 0); \
  __builtin_amdgcn_s_setprio(0);

#define LAYER_LOOP(WT, NS, CSTEPS)                                            \
  _Pragma("unroll")                                                           \
  for (int m = 0; m < 8; ++m)                                                 \
    _Pragma("unroll")                                                         \
    for (int n = 0; n < 4; ++n) acc[m][n] = (f32x4){0.f, 0.f, 0.f, 0.f};      \
  _Pragma("unroll 1")                                                         \
  for (int s = 0; s < (NS); ++s) {                                            \
    READF(aC, bC, s, CSTEPS)                                                  \
    __builtin_amdgcn_sched_barrier(0);                                        \
    asm volatile("s_waitcnt lgkmcnt(0)" ::: "memory");                        \
    __builtin_amdgcn_sched_barrier(0);                                        \
    __builtin_amdgcn_s_barrier();                                             \
    __builtin_amdgcn_sched_barrier(0);                                        \
    if (s + 1 < (NS)) STAGEC(WT, s + 1)                                       \
    __builtin_amdgcn_sched_barrier(0);                                        \
    MFMA32(aC, bC)                                                            \
    __builtin_amdgcn_sched_barrier(0);                                        \
    asm volatile("s_waitcnt vmcnt(0)" ::: "memory");                          \
    __builtin_amdgcn_s_barrier();                                             \
    __builtin_amdgcn_sched_barrier(0);                                        \
  }

// epilogue: acc -> activation tile (bias+relu, f16, XOR-swizzled), in place
#define EPI_LDS(BIAS, LOUT)                                                   \
  {                                                                           \
    _Pragma("unroll")                                                         \
    for (int n = 0; n < 4; ++n) {                                             \
      const int co = wc0 + 16 * n + lr;                                       \
      const float e = (BIAS)[co];                                             \
      const int sl = co >> 3, el = co & 7;                                    \
      _Pragma("unroll")                                                       \
      for (int m = 0; m < 8; ++m)                                             \
        _Pragma("unroll")                                                     \
        for (int r = 0; r < 4; ++r) {                                         \
          const int l = 16 * m + lh * 4 + r;                                  \
          if (l < (LOUT)) {                                                   \
            float v = fmaxf(acc[m][n][r] + e, 0.f);                           \
            ins[l * 256 + (((sl) ^ (l & 7)) << 3) + el] = (f16)v;             \
          }                                                                   \
        }                                                                     \
    }                                                                         \
  }

// layer boundary: stage next layer chunk 0 (latency hides under EPI VALU);
// EPI in-place; drain; barrier.
#define BOUNDARY(BIAS, LOUT, NEXTWT)                                          \
  STAGEC(NEXTWT, 0)                                                           \
  __builtin_amdgcn_sched_barrier(0);                                          \
  EPI_LDS(BIAS, LOUT)                                                         \
  __builtin_amdgcn_sched_barrier(0);                                          \
  asm volatile("s_waitcnt vmcnt(0) lgkmcnt(0)" ::: "memory");                 \
  __builtin_amdgcn_s_barrier();                                               \
  __builtin_amdgcn_sched_barrier(0);

__global__ __launch_bounds__(256, 2) void fused_conv(
        const float* __restrict__ xin,
        const f16* __restrict__ wpw,  const float* __restrict__ bp,
        const f16* __restrict__ wct1, const float* __restrict__ b1,
        const f16* __restrict__ wct2, const float* __restrict__ b2,
        const f16* __restrict__ wct3, const float* __restrict__ b3,
        f16* __restrict__ h3out) {
    __shared__ f16 ins[128 * 256];               // 65,536 B
    __shared__ f16 wlds[8192];                   // 16,384 B -> total 80 KB

    const int b    = blockIdx.x;
    const int tid  = threadIdx.x;
    const int lane = tid & 63, w = tid >> 6;     // 4 waves
    const int wc0  = w * 64;                     // wave's 64-co quarter
    const int lr   = lane & 15, lh = lane >> 4;

    f32x4 acc[8][4];
    f16x8 aC[8], bC[4];

    // prologue: stage pw chunk 0; stage A tile (128 rows) from fp32 x
    STAGEC(wpw, 0)
    {
        const float* xr = xin + (size_t)b * 8192;
        for (int u = tid; u < 128 * 16; u += 256) {
            int r = u >> 4, sl = u & 15;
            int off = (sl < 8)
                ? ((r + 1 < 128 ? (r + 1) * 64 : 127 * 64) + sl * 8)
                : (sl - 8) * 8;                  // x0 block
            float4 v0 = *(const float4*)(xr + off);
            float4 v1 = *(const float4*)(xr + off + 4);
            f16x8 h = { (f16)v0.x, (f16)v0.y, (f16)v0.z, (f16)v0.w,
                        (f16)v1.x, (f16)v1.y, (f16)v1.z, (f16)v1.w };
            *(f16x8*)(ins + r * 256 + ((sl ^ (r & 7)) << 3)) = h;
        }
    }
    __syncthreads();                             // drains everything

    // ---- pointwise (K=128 = 4 chunks; taps k=0 only, rows <= 127) ----
    LAYER_LOOP(wpw, 4, 4)
    BOUNDARY(bp, L0_, wct1)

    // ---- conv1 ----
    LAYER_LOOP(wct1, 24, 8)
    BOUNDARY(b1, L1_, wct2)

    // ---- conv2 ----
    LAYER_LOOP(wct2, 24, 8)
    BOUNDARY(b2, L2_, wct3)

    // ---- conv3 -> global h3 [l][co] (FC1-ready) ----
    LAYER_LOOP(wct3, 24, 8)
    {
        f16* ob = h3out + (size_t)b * L3_ * NCH;
#pragma unroll
        for (int n = 0; n < 4; ++n) {
            const int co = wc0 + 16 * n + lr;
            const float e = b3[co];
#pragma unroll
            for (int m = 0; m < 8; ++m)
#pragma unroll
                for (int r = 0; r < 4; ++r) {
                    const int l = 16 * m + lh * 4 + r;
                    if (l < L3_) {
                        float v = fmaxf(acc[m][n][r] + e, 0.f);
                        ob[(size_t)l * NCH + co] = (f16)v;
                    }
                }
        }
    }
}

// ---------------------------------------------------------------------------
// FC1, BK=64 (R18 verbatim): tile 128b x 256f, 512 thr = 8 waves.
// ---------------------------------------------------------------------------
__global__ __launch_bounds__(512, 1) void fc1k(const f16* __restrict__ A,
                                               const f16* __restrict__ Bw,
                                               float* __restrict__ part,
                                               int CB) {
    __shared__ f16 Asl[2 * 8192];                // 2 x (128b x 64k)
    __shared__ f16 Bsl[2 * 16384];               // 2 x (256f x 64k)
    const int m0 = blockIdx.x * 128, n0 = blockIdx.y * 256, sp = blockIdx.z;
    const int tid  = threadIdx.x;
    const int lane = tid & 63, w = tid >> 6;
    const int wb0  = (w >> 2) * 64, wf0 = (w & 3) * 64;
    const int lr   = lane & 15, lh = lane >> 4;
    const int ck0  = sp * KPS;

    auto stage = [&](int s2, int buf) {
        const int k0 = (ck0 + 2 * s2) * 32;      // f16 col base, 64 wide
#pragma unroll
        for (int j = 0; j < 2; ++j) {            // A: 1024 units
            int u = j * 512 + tid;
            int row = u >> 3, cu = u & 7;
            int cs = cu ^ (row & 7);
            gl16(A + (size_t)(m0 + row) * FCK + k0 + cs * 8,
                 Asl + buf * 8192 + (size_t)(j * 512 + w * 64) * 8);
        }
#pragma unroll
        for (int j = 0; j < 4; ++j) {            // B: 2048 units
            int u = j * 512 + tid;
            int row = u >> 3, cu = u & 7;
            int cs = cu ^ (row & 7);
            gl16(Bw + (size_t)(n0 + row) * FCK + k0 + cs * 8,
                 Bsl + buf * 16384 + (size_t)(j * 512 + w * 64) * 8);
        }
    };

    f32x4 acc[4][4];
#pragma unroll
    for (int m = 0; m < 4; ++m)
#pragma unroll
        for (int n = 0; n < 4; ++n) acc[m][n] = (f32x4){0.f, 0.f, 0.f, 0.f};

    stage(0, 0);
    __syncthreads();

#pragma unroll 1
    for (int s = 0; s < NS_FC; ++s) {
        const int cur = s & 1;
        if (s + 1 < NS_FC) stage(s + 1, cur ^ 1);
        __builtin_amdgcn_sched_barrier(0);
#pragma unroll
        for (int kk = 0; kk < 2; ++kk) {
            f16x8 a[4], bf[4];
#pragma unroll
            for (int m = 0; m < 4; ++m) {
                const int row = wb0 + 16 * m + lr;
                const int un = (kk * 4 + lh) ^ (row & 7);
                a[m] = *(const f16x8*)(Asl + cur * 8192 + row * 64 + un * 8);
            }
#pragma unroll
            for (int n = 0; n < 4; ++n) {
                const int row = wf0 + 16 * n + lr;
                const int un = (kk * 4 + lh) ^ (row & 7);
                bf[n] = *(const f16x8*)(Bsl + cur * 16384 + row * 64 + un * 8);
            }
            __builtin_amdgcn_s_setprio(1);
#pragma unroll
            for (int m = 0; m < 4; ++m)
#pragma unroll
                for (int n = 0; n < 4; ++n)
                    acc[m][n] = __builtin_amdgcn_mfma_f32_16x16x32_f16(
                        a[m], bf[n], acc[m][n], 0, 0, 0);
            __builtin_amdgcn_s_setprio(0);
        }
        __builtin_amdgcn_sched_barrier(0);
        asm volatile("s_waitcnt vmcnt(0)" ::: "memory");
        __builtin_amdgcn_sched_barrier(0);
        __builtin_amdgcn_s_barrier();
    }

#pragma unroll
    for (int m = 0; m < 4; ++m)
#pragma unroll
        for (int n = 0; n < 4; ++n)
#pragma unroll
            for (int r = 0; r < 4; ++r) {
                const int bl = m0 + wb0 + 16 * m + lh * 4 + r;
                const int f  = n0 + wf0 + 16 * n + lr;
                part[((size_t)sp * CB + bl) * F1_ + f] = acc[m][n][r];
            }
}

// ---------------------------------------------------------------------------
// fused reduce + fc2: out[b] = bf2 + relu(bf1 + sum_sp part)[.] . Wf2
// ---------------------------------------------------------------------------
__global__ __launch_bounds__(512) void fcout(const float* __restrict__ part,
                                             const float* __restrict__ bf1,
                                             const float* __restrict__ Wf2,
                                             const float* __restrict__ bf2,
                                             float* __restrict__ out,
                                             int CB) {
    __shared__ float red[8];
    const int m = blockIdx.x;
    const int f = threadIdx.x;
    float s = bf1[f];
#pragma unroll
    for (int sp = 0; sp < SPLIT; ++sp)
        s += part[((size_t)sp * CB + m) * F1_ + f];
    float p = fmaxf(s, 0.f) * Wf2[f];
#pragma unroll
    for (int o = 32; o > 0; o >>= 1) p += __shfl_xor(p, o);
    if ((f & 63) == 0) red[f >> 6] = p;
    __syncthreads();
    if (f < 8) {
        float v = red[f];
        v += __shfl_xor(v, 1);
        v += __shfl_xor(v, 2);
        v += __shfl_xor(v, 4);
        if (f == 0) out[m] = v + bf2[0];
    }
}

// ---------------------------------------------------------------------------
extern "C" void kernel_launch(void* const* d_in, const int* in_sizes, int n_in,
                              void* d_out, int out_size, void* d_ws, size_t ws_size,
                              hipStream_t stream) {
    const float* x   = (const float*)d_in[0];
    const float* Wp  = (const float*)d_in[1];
    const float* bp  = (const float*)d_in[2];
    const float* W1  = (const float*)d_in[3];
    const float* b1  = (const float*)d_in[4];
    const float* W2  = (const float*)d_in[5];
    const float* b2  = (const float*)d_in[6];
    const float* W3  = (const float*)d_in[7];
    const float* b3  = (const float*)d_in[8];
    const float* Wf1 = (const float*)d_in[9];
    const float* bf1 = (const float*)d_in[10];
    const float* Wf2 = (const float*)d_in[11];
    const float* bf2 = (const float*)d_in[12];
    float* out = (float*)d_out;

    // ---- workspace layout ----------------------------------------------
    char* base = (char*)d_ws;
    size_t off = 0;
    auto alloc = [&](size_t bytes) {
        size_t o = off; off = (off + bytes + 255) & ~(size_t)255; return o;
    };
    const size_t o_wpw  = alloc((size_t)NCH * 128 * 2);
    const size_t o_wct1 = alloc((size_t)NCH * 768 * 2);
    const size_t o_wct2 = alloc((size_t)NCH * 768 * 2);
    const size_t o_wct3 = alloc((size_t)NCH * 768 * 2);
    const size_t o_wf1h = alloc((size_t)F1_ * FCK * 2);
    const size_t fixed  = off;

    int CB = 0;
    const int cand[5] = {2048, 1024, 512, 256, 128};
    for (int i = 0; i < 5; ++i) {
        size_t c = (size_t)cand[i];
        size_t need = fixed
            + (((size_t)SPLIT * c * F1_ * 4 + 255) & ~(size_t)255)   // part
            + ((c * (size_t)L3_ * NCH * 2 + 255) & ~(size_t)255);    // h3
        if (need <= ws_size) { CB = cand[i]; break; }
    }
    if (CB == 0) return;
    const int nchunk = B_SZ / CB;

    const size_t o_part = alloc((size_t)SPLIT * CB * F1_ * 4);
    const size_t o_h3   = alloc((size_t)CB * L3_ * NCH * 2);

    f16*   wpw  = (f16*)(base + o_wpw);
    f16*   wct1 = (f16*)(base + o_wct1);
    f16*   wct2 = (f16*)(base + o_wct2);
    f16*   wct3 = (f16*)(base + o_wct3);
    f16*   wf1h = (f16*)(base + o_wf1h);
    float* part = (float*)(base + o_part);
    f16*   h3   = (f16*)(base + o_h3);

    // ---- preps ---------------------------------------------------------
    prep_w<<<2432, 256, 0, stream>>>(Wp, W1, W2, W3, wpw, wct1, wct2, wct3);
    prep_wf1k<<<F1_, 256, 0, stream>>>(Wf1, wf1h);

    // ---- chunked pipeline ----------------------------------------------
    for (int c = 0; c < nchunk; ++c) {
        const size_t b0 = (size_t)c * CB;
        fused_conv<<<CB, 256, 0, stream>>>(x + b0 * 8192,
                                           wpw, bp, wct1, b1, wct2, b2,
                                           wct3, b3, h3);
        fc1k<<<dim3(CB / 128, 2, SPLIT), 512, 0, stream>>>(h3, wf1h, part, CB);
        fcout<<<CB, 512, 0, stream>>>(part, bf1, Wf2, bf2, out + b0, CB);
    }
}

// Round 21
// 631.123 us; speedup vs baseline: 1.0973x; 1.0973x over previous
//
#include <hip/hip_runtime.h>

typedef _Float16 f16;
typedef _Float16 f16x8 __attribute__((ext_vector_type(8)));
typedef _Float16 f16x4 __attribute__((ext_vector_type(4)));
typedef float    f32x4 __attribute__((ext_vector_type(4)));

#define B_SZ   2048
#define NCH    256
#define L0_    127
#define L1_    125
#define L2_    123
#define L3_    121
#define F1_    512
#define FCK    30976
#define FCK2   31744       // K padded to 124*256 (3 zero rows) for even split
#define SPLIT  16          // 16 * 62 chunks = 992 (24 pad chunks of zeros)
#define KPS2   62
#define NS_FC  31
#define BUFF   16384       // f16 per B buffer (2 chunks)

// async global->LDS, 16B per lane; dest = wave-uniform base + lane*16
__device__ __forceinline__ void gl16(const f16* g, f16* l) {
    __builtin_amdgcn_global_load_lds(
        (const __attribute__((address_space(1))) void*)g,
        (__attribute__((address_space(3))) void*)l, 16, 0, 0);
}

// ---------------------------------------------------------------------------
// merged weight prep, CHUNK-MAJOR [ks32][co][32]:
// wpw: 4 chunks (K=128: [wp1 | wp0]); wct1..3: 24 chunks (kt = k*256+ci)
// ---------------------------------------------------------------------------
__global__ __launch_bounds__(256) void prep_w(const float* __restrict__ Wp,
                                              const float* __restrict__ W1,
                                              const float* __restrict__ W2,
                                              const float* __restrict__ W3,
                                              f16* __restrict__ wpw,
                                              f16* __restrict__ wct1,
                                              f16* __restrict__ wct2,
                                              f16* __restrict__ wct3) {
    int g = blockIdx.x;
    if (g < 128) {
        int idx = g * 256 + threadIdx.x;        // [ck][co][w5]
        int ck = idx >> 13, co = (idx >> 5) & 255, w5 = idx & 31;
        int j = ck * 32 + w5;                   // ci 0..127
        float v = (j < 64) ? Wp[co * 128 + j * 2 + 1]
                           : Wp[co * 128 + (j - 64) * 2];
        wpw[idx] = (f16)v;
        return;
    }
    int g2 = g - 128;
    const float* W = (g2 < 768) ? W1 : (g2 < 1536) ? W2 : W3;
    f16* dst = (g2 < 768) ? wct1 : (g2 < 1536) ? wct2 : wct3;
    int idx = (g2 % 768) * 256 + threadIdx.x;   // [ck][co][w5]
    int ck = idx >> 13, co = (idx >> 5) & 255, w5 = idx & 31;
    int kt = ck * 32 + w5;
    int k = kt >> 8, ci = kt & 255;
    dst[idx] = (f16)W[((size_t)co * NCH + ci) * 3 + k];
}

// Wf1[f][co*121+l] -> wf1h[f][l*256+co] with rows l=121..123 zero (K pad)
__global__ __launch_bounds__(256) void prep_wf1k(const float* __restrict__ Wf1,
                                                 f16* __restrict__ wf1h) {
    __shared__ f16 t[NCH * 122];
    const int f = blockIdx.x, tid = threadIdx.x;
    const float* src = Wf1 + (size_t)f * FCK;
    for (int idx = tid; idx < FCK; idx += 256) {
        int co = idx / 121, l = idx - co * 121;
        t[co * 122 + l] = (f16)src[idx];
    }
    __syncthreads();
    f16* dst = wf1h + (size_t)f * FCK2;
    for (int idx = tid; idx < FCK2; idx += 256) {
        int l = idx >> 8, co = idx & 255;
        dst[idx] = (l < 121) ? t[co * 122 + l] : (f16)0.f;
    }
}

// ---------------------------------------------------------------------------
// FUSED pw+conv1+conv2+conv3 (R18 protocol, BK=64, 1 barrier/step).
// Block = one b, 256 thr = 4 waves (co quarters), wave tile 128l x 64co.
// Activation tile [130][256] LDS-resident, in-place layer updates.
// conv3 epilogue: via LDS, then COALESCED f16x8 copy to h3 (R21 change),
// rows 121..123 written as zeros (FC1 K-pad).
// ---------------------------------------------------------------------------
#define STAGEB(WT, S2, BUF)                                                   \
  {                                                                           \
    const f16* src0_ = (WT) + (size_t)(2 * (S2)) * 8192;                      \
    _Pragma("unroll")                                                         \
    for (int j = 0; j < 8; ++j) {                                             \
        int u_ = j * 256 + w * 64 + lane;                                     \
        int row_ = u_ >> 2, cu_ = u_ & 3;                                     \
        int cs_ = cu_ ^ ((row_ >> 2) & 3);                                    \
        gl16(src0_ + row_ * 32 + cs_ * 8,                                     \
             wlds + (BUF) * BUFF + (size_t)(j * 256 + w * 64) * 8);           \
    }                                                                         \
  }

#define GEMM_LAYER(WT, NS, CSTEPS)                                            \
  _Pragma("unroll")                                                           \
  for (int m = 0; m < 8; ++m)                                                 \
    _Pragma("unroll")                                                         \
    for (int n = 0; n < 4; ++n) acc[m][n] = (f32x4){0.f, 0.f, 0.f, 0.f};      \
  _Pragma("unroll 1")                                                         \
  for (int s = 0; s < (NS); ++s) {                                            \
    const int cur = s & 1;                                                    \
    if (s + 1 < (NS)) STAGEB(WT, s + 1, cur ^ 1)                              \
    __builtin_amdgcn_sched_barrier(0);                                        \
    _Pragma("unroll")                                                         \
    for (int kk = 0; kk < 2; ++kk) {                                          \
      const int ks32 = 2 * s + kk;                                            \
      const int k = ks32 / (CSTEPS), cb = (ks32 % (CSTEPS)) * 4;              \
      f16x8 a[8], bf[4];                                                      \
      _Pragma("unroll")                                                       \
      for (int m = 0; m < 8; ++m) {                                           \
        const int r_ = 16 * m + lr + k;                                       \
        a[m] = *(const f16x8*)(ins + r_ * 256 + (((cb + lh) ^ (r_ & 7)) << 3)); \
      }                                                                       \
      _Pragma("unroll")                                                       \
      for (int n = 0; n < 4; ++n) {                                           \
        const int co = wc0 + 16 * n + lr;                                     \
        bf[n] = *(const f16x8*)(wlds + cur * BUFF + kk * 8192                 \
                                + (co * 4 + (lh ^ ((co >> 2) & 3))) * 8);     \
      }                                                                       \
      __builtin_amdgcn_s_setprio(1);                                          \
      _Pragma("unroll")                                                       \
      for (int n = 0; n < 4; ++n)                                             \
        _Pragma("unroll")                                                     \
        for (int m = 0; m < 8; ++m)                                           \
          acc[m][n] = __builtin_amdgcn_mfma_f32_16x16x32_f16(a[m], bf[n],     \
                                                             acc[m][n], 0, 0, 0); \
      __builtin_amdgcn_s_setprio(0);                                          \
    }                                                                         \
    __builtin_amdgcn_sched_barrier(0);                                        \
    asm volatile("s_waitcnt vmcnt(0)" ::: "memory");                          \
    __builtin_amdgcn_sched_barrier(0);                                        \
    __builtin_amdgcn_s_barrier();                                             \
  }

// epilogue: acc -> activation tile (bias+relu, f16, XOR-swizzled), in place
#define EPI_LDS(BIAS, LOUT)                                                   \
  {                                                                           \
    _Pragma("unroll")                                                         \
    for (int n = 0; n < 4; ++n) {                                             \
      const int co = wc0 + 16 * n + lr;                                       \
      const float e = (BIAS)[co];                                             \
      const int sl = co >> 3, el = co & 7;                                    \
      _Pragma("unroll")                                                       \
      for (int m = 0; m < 8; ++m)                                             \
        _Pragma("unroll")                                                     \
        for (int r = 0; r < 4; ++r) {                                         \
          const int l = 16 * m + lh * 4 + r;                                  \
          if (l < (LOUT)) {                                                   \
            float v = fmaxf(acc[m][n][r] + e, 0.f);                           \
            ins[l * 256 + (((sl) ^ (l & 7)) << 3) + el] = (f16)v;             \
          }                                                                   \
        }                                                                     \
    }                                                                         \
  }

__global__ __launch_bounds__(256, 1) void fused_conv(
        const float* __restrict__ xin,
        const f16* __restrict__ wpw,  const float* __restrict__ bp,
        const f16* __restrict__ wct1, const float* __restrict__ b1,
        const f16* __restrict__ wct2, const float* __restrict__ b2,
        const f16* __restrict__ wct3, const float* __restrict__ b3,
        f16* __restrict__ h3out) {
    __shared__ f16 ins[130 * 256];
    __shared__ f16 wlds[2 * BUFF];

    const int b    = blockIdx.x;
    const int tid  = threadIdx.x;
    const int lane = tid & 63, w = tid >> 6;     // 4 waves
    const int wc0  = w * 64;                     // wave's 64-co quarter
    const int lr   = lane & 15, lh = lane >> 4;

    f32x4 acc[8][4];

    // prologue: stage pw B chunk 0, then x -> act tile (row r = [xr(r+1)|x0])
    STAGEB(wpw, 0, 0)
    {
        const float* xr = xin + (size_t)b * 8192;
        for (int u = tid; u < 130 * 16; u += 256) {
            int r = u >> 4, sl = u & 15;
            int off = (sl < 8)
                ? ((r + 1 < 128 ? (r + 1) * 64 : 127 * 64) + sl * 8)
                : (sl - 8) * 8;                  // x0 block
            float4 v0 = *(const float4*)(xr + off);
            float4 v1 = *(const float4*)(xr + off + 4);
            f16x8 h = { (f16)v0.x, (f16)v0.y, (f16)v0.z, (f16)v0.w,
                        (f16)v1.x, (f16)v1.y, (f16)v1.z, (f16)v1.w };
            *(f16x8*)(ins + r * 256 + ((sl ^ (r & 7)) << 3)) = h;
        }
    }
    __syncthreads();                             // drains stage + act writes

    // ---- pointwise (K=128, 2 BK-64 steps) ----
    GEMM_LAYER(wpw, 2, 4)
    STAGEB(wct1, 0, 0)
    EPI_LDS(bp, L0_)
    asm volatile("s_waitcnt vmcnt(0) lgkmcnt(0)" ::: "memory");
    __builtin_amdgcn_s_barrier();

    // ---- conv1 ----
    GEMM_LAYER(wct1, 12, 8)
    STAGEB(wct2, 0, 0)
    EPI_LDS(b1, L1_)
    asm volatile("s_waitcnt vmcnt(0) lgkmcnt(0)" ::: "memory");
    __builtin_amdgcn_s_barrier();

    // ---- conv2 ----
    GEMM_LAYER(wct2, 12, 8)
    STAGEB(wct3, 0, 0)
    EPI_LDS(b2, L2_)
    asm volatile("s_waitcnt vmcnt(0) lgkmcnt(0)" ::: "memory");
    __builtin_amdgcn_s_barrier();

    // ---- conv3: EPI into LDS, then COALESCED copy to h3 (124 rows) ----
    GEMM_LAYER(wct3, 12, 8)
    EPI_LDS(b3, L3_)
    asm volatile("s_waitcnt lgkmcnt(0)" ::: "memory");
    __builtin_amdgcn_s_barrier();
    {
        f16* ob = h3out + (size_t)b * FCK2;
        const f16x8 z = { (f16)0.f, (f16)0.f, (f16)0.f, (f16)0.f,
                          (f16)0.f, (f16)0.f, (f16)0.f, (f16)0.f };
        for (int u = tid; u < 124 * 32; u += 256) {
            int r = u >> 5, sl = u & 31;
            f16x8 v = (r < L3_)
                ? *(const f16x8*)(ins + r * 256 + ((sl ^ (r & 7)) << 3))
                : z;
            *(f16x8*)(ob + r * 256 + sl * 8) = v;
        }
    }
}

// ---------------------------------------------------------------------------
// FC1, BK=64, K padded to FCK2 (no tail): tile 128b x 256f, 512 thr, 8 waves.
// SPLIT=16 -> 512 blocks = exactly 2/CU, one round.
// ---------------------------------------------------------------------------
__global__ __launch_bounds__(512, 1) void fc1k(const f16* __restrict__ A,
                                               const f16* __restrict__ Bw,
                                               float* __restrict__ part,
                                               int CB) {
    __shared__ f16 Asl[2 * 8192];                // 2 x (128b x 64k)
    __shared__ f16 Bsl[2 * 16384];               // 2 x (256f x 64k)
    const int m0 = blockIdx.x * 128, n0 = blockIdx.y * 256, sp = blockIdx.z;
    const int tid  = threadIdx.x;
    const int lane = tid & 63, w = tid >> 6;
    const int wb0  = (w >> 2) * 64, wf0 = (w & 3) * 64;
    const int lr   = lane & 15, lh = lane >> 4;
    const int ck0  = sp * KPS2;

    auto stage = [&](int s2, int buf) {
        const int k0 = (ck0 + 2 * s2) * 32;      // f16 col base, 64 wide
#pragma unroll
        for (int j = 0; j < 2; ++j) {            // A: 1024 units
            int u = j * 512 + tid;
            int row = u >> 3, cu = u & 7;
            int cs = cu ^ (row & 7);
            gl16(A + (size_t)(m0 + row) * FCK2 + k0 + cs * 8,
                 Asl + buf * 8192 + (size_t)(j * 512 + w * 64) * 8);
        }
#pragma unroll
        for (int j = 0; j < 4; ++j) {            // B: 2048 units
            int u = j * 512 + tid;
            int row = u >> 3, cu = u & 7;
            int cs = cu ^ (row & 7);
            gl16(Bw + (size_t)(n0 + row) * FCK2 + k0 + cs * 8,
                 Bsl + buf * 16384 + (size_t)(j * 512 + w * 64) * 8);
        }
    };

    f32x4 acc[4][4];
#pragma unroll
    for (int m = 0; m < 4; ++m)
#pragma unroll
        for (int n = 0; n < 4; ++n) acc[m][n] = (f32x4){0.f, 0.f, 0.f, 0.f};

    stage(0, 0);
    __syncthreads();

#pragma unroll 1
    for (int s = 0; s < NS_FC; ++s) {
        const int cur = s & 1;
        if (s + 1 < NS_FC) stage(s + 1, cur ^ 1);
        __builtin_amdgcn_sched_barrier(0);
#pragma unroll
        for (int kk = 0; kk < 2; ++kk) {
            f16x8 a[4], bf[4];
#pragma unroll
            for (int m = 0; m < 4; ++m) {
                const int row = wb0 + 16 * m + lr;
                const int un = (kk * 4 + lh) ^ (row & 7);
                a[m] = *(const f16x8*)(Asl + cur * 8192 + row * 64 + un * 8);
            }
#pragma unroll
            for (int n = 0; n < 4; ++n) {
                const int row = wf0 + 16 * n + lr;
                const int un = (kk * 4 + lh) ^ (row & 7);
                bf[n] = *(const f16x8*)(Bsl + cur * 16384 + row * 64 + un * 8);
            }
            __builtin_amdgcn_s_setprio(1);
#pragma unroll
            for (int m = 0; m < 4; ++m)
#pragma unroll
                for (int n = 0; n < 4; ++n)
                    acc[m][n] = __builtin_amdgcn_mfma_f32_16x16x32_f16(
                        a[m], bf[n], acc[m][n], 0, 0, 0);
            __builtin_amdgcn_s_setprio(0);
        }
        __builtin_amdgcn_sched_barrier(0);
        asm volatile("s_waitcnt vmcnt(0)" ::: "memory");
        __builtin_amdgcn_sched_barrier(0);
        __builtin_amdgcn_s_barrier();
    }

#pragma unroll
    for (int m = 0; m < 4; ++m)
#pragma unroll
        for (int n = 0; n < 4; ++n)
#pragma unroll
            for (int r = 0; r < 4; ++r) {
                const int bl = m0 + wb0 + 16 * m + lh * 4 + r;
                const int f  = n0 + wf0 + 16 * n + lr;
                part[((size_t)sp * CB + bl) * F1_ + f] = acc[m][n][r];
            }
}

// ---------------------------------------------------------------------------
// fused reduce + fc2: out[b] = bf2 + relu(bf1 + sum_sp part)[.] . Wf2
// ---------------------------------------------------------------------------
__global__ __launch_bounds__(512) void fcout(const float* __restrict__ part,
                                             const float* __restrict__ bf1,
                                             const float* __restrict__ Wf2,
                                             const float* __restrict__ bf2,
                                             float* __restrict__ out,
                                             int CB) {
    __shared__ float red[8];
    const int m = blockIdx.x;
    const int f = threadIdx.x;
    float s = bf1[f];
#pragma unroll
    for (int sp = 0; sp < SPLIT; ++sp)
        s += part[((size_t)sp * CB + m) * F1_ + f];
    float p = fmaxf(s, 0.f) * Wf2[f];
#pragma unroll
    for (int o = 32; o > 0; o >>= 1) p += __shfl_xor(p, o);
    if ((f & 63) == 0) red[f >> 6] = p;
    __syncthreads();
    if (f < 8) {
        float v = red[f];
        v += __shfl_xor(v, 1);
        v += __shfl_xor(v, 2);
        v += __shfl_xor(v, 4);
        if (f == 0) out[m] = v + bf2[0];
    }
}

// ---------------------------------------------------------------------------
extern "C" void kernel_launch(void* const* d_in, const int* in_sizes, int n_in,
                              void* d_out, int out_size, void* d_ws, size_t ws_size,
                              hipStream_t stream) {
    const float* x   = (const float*)d_in[0];
    const float* Wp  = (const float*)d_in[1];
    const float* bp  = (const float*)d_in[2];
    const float* W1  = (const float*)d_in[3];
    const float* b1  = (const float*)d_in[4];
    const float* W2  = (const float*)d_in[5];
    const float* b2  = (const float*)d_in[6];
    const float* W3  = (const float*)d_in[7];
    const float* b3  = (const float*)d_in[8];
    const float* Wf1 = (const float*)d_in[9];
    const float* bf1 = (const float*)d_in[10];
    const float* Wf2 = (const float*)d_in[11];
    const float* bf2 = (const float*)d_in[12];
    float* out = (float*)d_out;

    // ---- workspace layout ----------------------------------------------
    char* base = (char*)d_ws;
    size_t off = 0;
    auto alloc = [&](size_t bytes) {
        size_t o = off; off = (off + bytes + 255) & ~(size_t)255; return o;
    };
    const size_t o_wpw  = alloc((size_t)NCH * 128 * 2);
    const size_t o_wct1 = alloc((size_t)NCH * 768 * 2);
    const size_t o_wct2 = alloc((size_t)NCH * 768 * 2);
    const size_t o_wct3 = alloc((size_t)NCH * 768 * 2);
    const size_t o_wf1h = alloc((size_t)F1_ * FCK2 * 2);
    const size_t fixed  = off;

    int CB = 0;
    const int cand[5] = {2048, 1024, 512, 256, 128};
    for (int i = 0; i < 5; ++i) {
        size_t c = (size_t)cand[i];
        size_t need = fixed
            + (((size_t)SPLIT * c * F1_ * 4 + 255) & ~(size_t)255)   // part
            + ((c * (size_t)FCK2 * 2 + 255) & ~(size_t)255);         // h3
        if (need <= ws_size) { CB = cand[i]; break; }
    }
    if (CB == 0) return;
    const int nchunk = B_SZ / CB;

    const size_t o_part = alloc((size_t)SPLIT * CB * F1_ * 4);
    const size_t o_h3   = alloc((size_t)CB * FCK2 * 2);

    f16*   wpw  = (f16*)(base + o_wpw);
    f16*   wct1 = (f16*)(base + o_wct1);
    f16*   wct2 = (f16*)(base + o_wct2);
    f16*   wct3 = (f16*)(base + o_wct3);
    f16*   wf1h = (f16*)(base + o_wf1h);
    float* part = (float*)(base + o_part);
    f16*   h3   = (f16*)(base + o_h3);

    // ---- preps ---------------------------------------------------------
    prep_w<<<2432, 256, 0, stream>>>(Wp, W1, W2, W3, wpw, wct1, wct2, wct3);
    prep_wf1k<<<F1_, 256, 0, stream>>>(Wf1, wf1h);

    // ---- chunked pipeline ----------------------------------------------
    for (int c = 0; c < nchunk; ++c) {
        const size_t b0 = (size_t)c * CB;
        fused_conv<<<CB, 256, 0, stream>>>(x + b0 * 8192,
                                           wpw, bp, wct1, b1, wct2, b2,
                                           wct3, b3, h3);
        fc1k<<<dim3(CB / 128, 2, SPLIT), 512, 0, stream>>>(h3, wf1h, part, CB);
        fcout<<<CB, 512, 0, stream>>>(part, bf1, Wf2, bf2, out + b0, CB);
    }
}